// Round 1
// baseline (68.739 us; speedup 1.0000x reference)
//
#include <hip/hip_runtime.h>
#include <math.h>

#define NB 384          // batch size B
#define ND4 64          // D/4 = 256/4
#define NW 6            // waves per block (384 threads)
#define NC 32           // label histogram slots (C=24, padded)
#define TMARGIN 0.3f

// R6: single fused kernel.
// Insight: num_valid = sum_c cnt_c*(cnt_c-1) over classes with cnt_c < B is a
// pure function of labels, so EVERY block computes the global normalizer
// independently from an LDS label histogram. Each block then contributes
// ssum/num_valid via one device-scope float atomicAdd to out[0] (zeroed by a
// 4-byte memset node). This deletes the triplet_final kernel node, its
// dispatch/gap latency, and all workspace traffic. No ticket, no threadfence
// (the mechanisms suspected in R3/R4's regression).
__global__ __launch_bounds__(NB) void triplet_fused(
    const float4* __restrict__ E4, const int* __restrict__ labels,
    float* __restrict__ out)
{
    const int a = blockIdx.x;
    const int t = threadIdx.x;
    const int w = t >> 6;     // wave id 0..5
    const int l = t & 63;     // lane id
    const int s = l & 7;      // sub-lane within 8-lane row group
    const int g = l >> 3;     // row group 0..7

    __shared__ float4 sa4[ND4];    // anchor embedding (1 KB)
    __shared__ float  sdist[NB];   // dist[a][:]
    __shared__ int    slabel[NB];
    __shared__ int    spos[NB];    // positive indices
    __shared__ int    shist[NC];   // label histogram (same in every block)
    __shared__ int    scount;
    __shared__ float  swred[NW];
    __shared__ float  snegmin;

    if (t == 0) scount = 0;
    if (t < NC) shist[t] = 0;
    if (t < ND4) sa4[t] = E4[a * ND4 + t];
    const int lt = labels[t];
    slabel[t] = lt;
    __syncthreads();
    // Histogram build; only read by thread 0 after later __syncthreads(), so
    // all LDS atomics are ordered-before the read.
    atomicAdd(&shist[lt], 1);

    // anchor float4s this sub-lane needs: sa4[s + 8j] (LDS broadcast reads)
    float4 u[8];
    #pragma unroll
    for (int j = 0; j < 8; ++j) u[j] = sa4[s + (j << 3)];

    // ---- phase 1: wave w computes rows [64w, 64w+64), 8 rows per iter ----
    #pragma unroll
    for (int i = 0; i < 8; ++i) {
        const int row = (w << 6) + (i << 3) + g;
        const float4* __restrict__ p = E4 + row * ND4 + s;
        float d = 0.f;
        #pragma unroll
        for (int j = 0; j < 8; ++j) {
            float4 v = p[j << 3];                      // lanes 0-7 cover 128B of row
            float dx = v.x - u[j].x, dy = v.y - u[j].y;
            float dz = v.z - u[j].z, dq = v.w - u[j].w;
            d += dx*dx + dy*dy + dz*dz + dq*dq;
        }
        d += __shfl_xor(d, 1, 64);                     // reduce within 8-lane group
        d += __shfl_xor(d, 2, 64);
        d += __shfl_xor(d, 4, 64);
        if (s == 0) sdist[row] = d;
    }
    __syncthreads();

    const int la = slabel[a];

    // ---- phase 2: negmin over row + collect positives ----
    float nm = (slabel[t] != la) ? sdist[t] : INFINITY;
    #pragma unroll
    for (int off = 32; off > 0; off >>= 1)
        nm = fminf(nm, __shfl_xor(nm, off, 64));
    if (l == 0) swred[w] = nm;
    if (slabel[t] == la && t != a) {
        int idx = atomicAdd(&scount, 1);
        spos[idx] = t;
    }
    __syncthreads();
    if (t == 0) {
        float m = swred[0];
        #pragma unroll
        for (int i = 1; i < NW; ++i) m = fminf(m, swred[i]);
        snegmin = m;
    }
    __syncthreads();

    const float negmin  = snegmin;
    const int   P       = scount;
    const bool  has_neg = (negmin < INFINITY);

    // ---- phase 3: semi-hard mining, one positive per wave ----
    float lsum = 0.f;
    if (has_neg) {
        for (int pi = w; pi < P; pi += NW) {
            const int   p  = spos[pi];
            const float dp = sdist[p];
            const float hi = dp + TMARGIN;
            float m = INFINITY;
            #pragma unroll
            for (int i = 0; i < NB / 64; ++i) {
                const int   n  = (i << 6) + l;
                const float dn = sdist[n];
                if ((slabel[n] != la) && (dn > dp) && (dn < hi))
                    m = fminf(m, dn);
            }
            #pragma unroll
            for (int off = 32; off > 0; off >>= 1)
                m = fminf(m, __shfl_xor(m, off, 64));
            if (l == 0) {
                const float dan = (m < INFINITY) ? m : negmin;
                lsum += fmaxf(dp - dan + TMARGIN, 0.f);
            }
        }
    }

    // ---- block reduce; one global atomic per block, normalizer computed locally ----
    __syncthreads();               // protect swred reuse; orders shist atomics too
    if (l == 0) swred[w] = lsum;
    __syncthreads();
    if (t == 0) {
        float ssum = swred[0];
        #pragma unroll
        for (int i = 1; i < NW; ++i) ssum += swred[i];
        if (ssum != 0.f) {
            // num_valid = sum over classes c with cnt_c < B of cnt_c*(cnt_c-1)
            int nv = 0;
            #pragma unroll
            for (int c = 0; c < NC; ++c) {
                const int n = shist[c];
                if (n < NB) nv += n * (n - 1);
            }
            atomicAdd(out, ssum / (float)(nv > 0 ? nv : 1));
        }
    }
}

extern "C" void kernel_launch(void* const* d_in, const int* in_sizes, int n_in,
                              void* d_out, int out_size, void* d_ws, size_t ws_size,
                              hipStream_t stream) {
    (void)in_sizes; (void)n_in; (void)d_ws; (void)ws_size; (void)out_size;
    const float4* emb  = (const float4*)d_in[0];   // (384, 256) fp32
    const int* labels  = (const int*)d_in[1];      // (384,) int32

    float* out = (float*)d_out;
    hipMemsetAsync(out, 0, sizeof(float), stream); // 4-byte memset node: out = 0
    triplet_fused<<<NB, NB, 0, stream>>>(emb, labels, out);
}

// Round 2
// 66.888 us; speedup vs baseline: 1.0277x; 1.0277x over previous
//
#include <hip/hip_runtime.h>
#include <math.h>

#define NB 384          // batch size B
#define ND4 64          // D/4 = 256/4
#define NW 6            // waves per block (384 threads)
#define NC 32           // label histogram slots (C=24, padded)
#define NA 2            // anchors per block
#define NBLK (NB/NA)    // 192 blocks -> <=1 block/CU, no tail imbalance
#define TMARGIN 0.3f

// R7: 2 anchors per block (192 blocks x 384 threads).
//  - kills the 384-on-256-CU 2x tail (128 CUs ran 2 blocks serially)
//  - halves chip-wide L2 traffic for E (151 MB -> 74 MB): each loaded row v
//    feeds BOTH anchors
//  - phase 1 uses the reference's own dot form d = sq_v + sq_a - 2*dot
//    (12 ops/float4 for 2 anchors vs 16 for two diff-squares), clamped at 0
//  - phases 2/3 fused for both anchors over the same 6 waves
//  - normalizer from LDS label histogram (pure function of labels); one
//    device atomicAdd per block into out[0] (zeroed by a 4-byte memset node)
__global__ __launch_bounds__(NB) void triplet_fused(
    const float4* __restrict__ E4, const int* __restrict__ labels,
    float* __restrict__ out)
{
    const int a0 = blockIdx.x * NA;       // anchors a0, a0+1 (rows contiguous)
    const int t = threadIdx.x;
    const int w = t >> 6;     // wave id 0..5
    const int l = t & 63;     // lane id
    const int s = l & 7;      // sub-lane within 8-lane row group
    const int g = l >> 3;     // row group 0..7

    __shared__ float4 sa4[NA][ND4];    // the two anchor embeddings (2 KB)
    __shared__ float  sdist[NA][NB];   // dist rows for both anchors (3 KB)
    __shared__ int    slabel[NB];
    __shared__ int    spos[NA][NB];    // positive indices per anchor
    __shared__ int    shist[NC];       // label histogram (same in every block)
    __shared__ int    scount[NA];
    __shared__ float  swred[NA][NW];
    __shared__ float  snegmin[NA];

    if (t < NA) scount[t] = 0;
    if (t < NC) shist[t] = 0;
    if (t < NA * ND4) ((float4*)sa4)[t] = E4[a0 * ND4 + t];  // rows a0,a0+1 contiguous
    const int lt = labels[t];
    slabel[t] = lt;
    __syncthreads();
    // histogram build; read by thread 0 only after later __syncthreads()
    atomicAdd(&shist[lt], 1);

    // anchor float4s this sub-lane needs: sa4[*][s + 8j] (LDS broadcast reads)
    float4 u0[8], u1[8];
    #pragma unroll
    for (int j = 0; j < 8; ++j) {
        u0[j] = sa4[0][s + (j << 3)];
        u1[j] = sa4[1][s + (j << 3)];
    }

    // squared norms of both anchors (redundant per 8-lane group; ~70 ops)
    float sqa0 = 0.f, sqa1 = 0.f;
    #pragma unroll
    for (int j = 0; j < 8; ++j) {
        sqa0 += u0[j].x*u0[j].x + u0[j].y*u0[j].y + u0[j].z*u0[j].z + u0[j].w*u0[j].w;
        sqa1 += u1[j].x*u1[j].x + u1[j].y*u1[j].y + u1[j].z*u1[j].z + u1[j].w*u1[j].w;
    }
    #pragma unroll
    for (int off = 1; off < 8; off <<= 1) {
        sqa0 += __shfl_xor(sqa0, off, 64);
        sqa1 += __shfl_xor(sqa1, off, 64);
    }

    // ---- phase 1: wave w computes rows [64w, 64w+64), 8 rows per iter ----
    #pragma unroll
    for (int i = 0; i < 8; ++i) {
        const int row = (w << 6) + (i << 3) + g;
        const float4* __restrict__ p = E4 + row * ND4 + s;
        float dot0 = 0.f, dot1 = 0.f, sqv = 0.f;
        #pragma unroll
        for (int j = 0; j < 8; ++j) {
            float4 v = p[j << 3];                      // lanes 0-7 cover 128B of row
            dot0 += v.x*u0[j].x + v.y*u0[j].y + v.z*u0[j].z + v.w*u0[j].w;
            dot1 += v.x*u1[j].x + v.y*u1[j].y + v.z*u1[j].z + v.w*u1[j].w;
            sqv  += v.x*v.x + v.y*v.y + v.z*v.z + v.w*v.w;
        }
        #pragma unroll
        for (int off = 1; off < 8; off <<= 1) {        // reduce within 8-lane group
            dot0 += __shfl_xor(dot0, off, 64);
            dot1 += __shfl_xor(dot1, off, 64);
            sqv  += __shfl_xor(sqv , off, 64);
        }
        if (s == 0) {
            sdist[0][row] = fmaxf(sqv + sqa0 - 2.f * dot0, 0.f);
            sdist[1][row] = fmaxf(sqv + sqa1 - 2.f * dot1, 0.f);
        }
    }
    __syncthreads();

    const int la0 = slabel[a0];
    const int la1 = slabel[a0 + 1];

    // ---- phase 2: negmin + positive lists for both anchors ----
    float nm0 = (lt != la0) ? sdist[0][t] : INFINITY;
    float nm1 = (lt != la1) ? sdist[1][t] : INFINITY;
    #pragma unroll
    for (int off = 32; off > 0; off >>= 1) {
        nm0 = fminf(nm0, __shfl_xor(nm0, off, 64));
        nm1 = fminf(nm1, __shfl_xor(nm1, off, 64));
    }
    if (l == 0) { swred[0][w] = nm0; swred[1][w] = nm1; }
    if (lt == la0 && t != a0)     spos[0][atomicAdd(&scount[0], 1)] = t;
    if (lt == la1 && t != a0 + 1) spos[1][atomicAdd(&scount[1], 1)] = t;
    __syncthreads();
    if (t < NA) {
        float m = swred[t][0];
        #pragma unroll
        for (int i = 1; i < NW; ++i) m = fminf(m, swred[t][i]);
        snegmin[t] = m;
    }
    __syncthreads();

    const float ng0 = snegmin[0], ng1 = snegmin[1];
    const int   P0  = scount[0],  P1  = scount[1];

    // ---- phase 3: semi-hard mining, combined positive list, 1 positive/wave ----
    float lsum = 0.f;
    const int total = P0 + P1;
    for (int pi = w; pi < total; pi += NW) {
        const int   which = (pi >= P0) ? 1 : 0;
        const float nmW   = which ? ng1 : ng0;
        if (nmW == INFINITY) continue;                 // anchor has no negative
        const int   la  = which ? la1 : la0;
        const float* __restrict__ dst = sdist[which];
        const int   p   = spos[which][which ? pi - P0 : pi];
        const float dp  = dst[p];
        const float hi  = dp + TMARGIN;
        float m = INFINITY;
        #pragma unroll
        for (int i = 0; i < NB / 64; ++i) {
            const int   n  = (i << 6) + l;
            const float dn = dst[n];
            if ((slabel[n] != la) && (dn > dp) && (dn < hi))
                m = fminf(m, dn);
        }
        #pragma unroll
        for (int off = 32; off > 0; off >>= 1)
            m = fminf(m, __shfl_xor(m, off, 64));
        if (l == 0) {
            const float dan = (m < INFINITY) ? m : nmW;
            lsum += fmaxf(dp - dan + TMARGIN, 0.f);
        }
    }

    // ---- block reduce; one global atomic per block, local normalizer ----
    __syncthreads();               // protect swred reuse; orders shist atomics
    if (l == 0) swred[0][w] = lsum;
    __syncthreads();
    if (t == 0) {
        float ssum = swred[0][0];
        #pragma unroll
        for (int i = 1; i < NW; ++i) ssum += swred[0][i];
        if (ssum != 0.f) {
            // num_valid = sum over classes c with cnt_c < B of cnt_c*(cnt_c-1)
            int nv = 0;
            #pragma unroll
            for (int c = 0; c < NC; ++c) {
                const int n = shist[c];
                if (n < NB) nv += n * (n - 1);
            }
            atomicAdd(out, ssum / (float)(nv > 0 ? nv : 1));
        }
    }
}

extern "C" void kernel_launch(void* const* d_in, const int* in_sizes, int n_in,
                              void* d_out, int out_size, void* d_ws, size_t ws_size,
                              hipStream_t stream) {
    (void)in_sizes; (void)n_in; (void)d_ws; (void)ws_size; (void)out_size;
    const float4* emb  = (const float4*)d_in[0];   // (384, 256) fp32
    const int* labels  = (const int*)d_in[1];      // (384,) int32

    float* out = (float*)d_out;
    hipMemsetAsync(out, 0, sizeof(float), stream); // 4-byte node: out = 0
    triplet_fused<<<NBLK, NB, 0, stream>>>(emb, labels, out);
}